// Round 1
// baseline (186.913 us; speedup 1.0000x reference)
//
#include <hip/hip_runtime.h>

typedef short bf16x8 __attribute__((ext_vector_type(8)));
typedef float f32x4 __attribute__((ext_vector_type(4)));
typedef unsigned short u16x8 __attribute__((ext_vector_type(8)));

#define MFMA16x16x32(a, b, c) __builtin_amdgcn_mfma_f32_16x16x32_bf16(a, b, c, 0, 0, 0)

__device__ __forceinline__ unsigned short f2bf(float f) {
  union { float f; unsigned u; } v; v.f = f;
  unsigned u = v.u + 0x7FFFu + ((v.u >> 16) & 1u);
  return (unsigned short)(u >> 16);
}

__device__ __forceinline__ void gload16(const void* g, void* l) {
  __builtin_amdgcn_global_load_lds((const __attribute__((address_space(1))) void*)g,
                                   (__attribute__((address_space(3))) void*)l, 16, 0, 0);
}

// ---------------- fp32 -> bf16 elementwise (x) ----------------
__global__ __launch_bounds__(256) void conv_bf16(const float* __restrict__ in,
                                                 unsigned short* __restrict__ out, int n8) {
  int i = blockIdx.x * 256 + threadIdx.x;
  if (i >= n8) return;
  const float4* p = reinterpret_cast<const float4*>(in + (long)i * 8);
  float4 a = p[0], b = p[1];
  u16x8 o;
  o[0] = f2bf(a.x); o[1] = f2bf(a.y); o[2] = f2bf(a.z); o[3] = f2bf(a.w);
  o[4] = f2bf(b.x); o[5] = f2bf(b.y); o[6] = f2bf(b.z); o[7] = f2bf(b.w);
  *reinterpret_cast<u16x8*>(out + (long)i * 8) = o;
}

// ---------------- transpose + convert: W[K][N] f32 -> Wt[N][K] bf16 ----------------
__global__ __launch_bounds__(256) void trans_f32_bf16(const float* __restrict__ W,
                                                      unsigned short* __restrict__ Wt,
                                                      int K, int N) {
  __shared__ float tile[32][33];
  int n0 = blockIdx.x << 5, k0 = blockIdx.y << 5;
  int tx = threadIdx.x, ty = threadIdx.y;  // 32 x 8
#pragma unroll
  for (int i = 0; i < 32; i += 8)
    tile[ty + i][tx] = W[(long)(k0 + ty + i) * N + n0 + tx];
  __syncthreads();
#pragma unroll
  for (int i = 0; i < 32; i += 8)
    Wt[(long)(n0 + ty + i) * K + k0 + tx] = f2bf(tile[tx][ty + i]);
}

// ---------------- GEMM: C[M,N] = A[M,K] @ Bt[N,K]^T + bias, bf16 inputs ----------------
// 128x128 tile, BK=32, 256 threads (4 waves, each 64x64), m97-style structure.
template <int BF16OUT>
__global__ __launch_bounds__(256) void gemm_bt(const unsigned short* __restrict__ A,
                                               const unsigned short* __restrict__ Bt,
                                               const float* __restrict__ bias,
                                               void* __restrict__ Cv,
                                               int M, int N, int K) {
  __shared__ unsigned short As[4096];  // [128][32]
  __shared__ unsigned short Bs[4096];  // [128][32]
  int t = threadIdx.x;
  int w = t >> 6, l = t & 63;
  int g = l >> 4, m16 = l & 15;
  int wr = w >> 1, wc = w & 1;
  long am0 = (long)blockIdx.y << 7;
  long bn0 = (long)blockIdx.x << 7;
  f32x4 acc[4][4];
#pragma unroll
  for (int i = 0; i < 4; ++i)
#pragma unroll
    for (int j = 0; j < 4; ++j) acc[i][j] = (f32x4){0.f, 0.f, 0.f, 0.f};

  for (int k0 = 0; k0 < K; k0 += 32) {
#pragma unroll
    for (int i = 0; i < 2; ++i) {
      int seg = i * 4 + w;
      int flat = (seg << 9) + (l << 3);   // element index within 128x32 tile
      int r_ = flat >> 5, c_ = flat & 31;
      gload16(A + (am0 + r_) * K + k0 + c_, &As[seg << 9]);
      gload16(Bt + (bn0 + r_) * K + k0 + c_, &Bs[seg << 9]);
    }
    __syncthreads();
    bf16x8 af[4], bfr[4];
#pragma unroll
    for (int im = 0; im < 4; ++im)
      af[im] = *(const bf16x8*)&As[((wr << 6) + (im << 4) + m16) * 32 + (g << 3)];
#pragma unroll
    for (int in = 0; in < 4; ++in)
      bfr[in] = *(const bf16x8*)&Bs[((wc << 6) + (in << 4) + m16) * 32 + (g << 3)];
#pragma unroll
    for (int im = 0; im < 4; ++im)
#pragma unroll
      for (int in = 0; in < 4; ++in)
        acc[im][in] = MFMA16x16x32(af[im], bfr[in], acc[im][in]);
    __syncthreads();
  }

#pragma unroll
  for (int im = 0; im < 4; ++im) {
#pragma unroll
    for (int in = 0; in < 4; ++in) {
      long col = bn0 + (wc << 6) + (in << 4) + m16;
      float bval = bias[col];
#pragma unroll
      for (int r = 0; r < 4; ++r) {
        long row = am0 + (wr << 6) + (im << 4) + (g << 2) + r;
        float v = acc[im][in][r] + bval;
        if (BF16OUT)
          ((unsigned short*)Cv)[row * N + col] = f2bf(v);
        else
          ((float*)Cv)[row * N + col] = v;
      }
    }
  }
}

// ---------------- causal flash attention ----------------
// qkv: bf16 [B*S][3072] (q | k | v, each head h at col h*64). out: bf16 [B*S][1024].
// grid: (B*H, S/16), block: 64 (one wave handles 16 q rows).
// Swapped QK^T: St = mfma(Kfrag, Qfrag) -> C layout col = q (lane&15), row = key.
// Key permutation in K-frag rows: key(m,T) = 8*(m>>2) + 4*T + (m&3), so that the
// two 16-key St tiles pack directly into the K=32 PV B-fragment (k = g*8+j).
__global__ __launch_bounds__(64) void attn_fwd(const unsigned short* __restrict__ qkv,
                                               unsigned short* __restrict__ out) {
  const int D3 = 3072;
  int b = blockIdx.x >> 4, h = blockIdx.x & 15;
  int q0 = blockIdx.y << 4;
  int l = threadIdx.x;
  int g = l >> 4, m16 = l & 15;
  long base = (long)b * 2048 * D3;
  int qrow = q0 + m16;

  const unsigned short* qp = qkv + base + (long)qrow * D3 + h * 64;
  bf16x8 qf0 = *(const bf16x8*)(qp + g * 8);
  bf16x8 qf1 = *(const bf16x8*)(qp + 32 + g * 8);

  f32x4 O[4];
#pragma unroll
  for (int d = 0; d < 4; ++d) O[d] = (f32x4){0.f, 0.f, 0.f, 0.f};
  float mrow = -1e30f, lsum = 0.f;

  const unsigned short* kb = qkv + base + 1024 + h * 64;
  const unsigned short* vb = qkv + base + 2048 + h * 64 + m16;
  int kend = q0 + 16;

  for (int kv0 = 0; kv0 < kend; kv0 += 32) {
    int key0 = kv0 + ((m16 >> 2) << 3) + (m16 & 3);  // tile0 permuted key for this lane-row
    const unsigned short* k0p = kb + (long)key0 * D3;
    const unsigned short* k1p = kb + (long)(key0 + 4) * D3;
    bf16x8 ka0 = *(const bf16x8*)(k0p + g * 8);
    bf16x8 ka1 = *(const bf16x8*)(k0p + 32 + g * 8);
    bf16x8 kb0 = *(const bf16x8*)(k1p + g * 8);
    bf16x8 kb1 = *(const bf16x8*)(k1p + 32 + g * 8);

    f32x4 st0 = (f32x4){0.f, 0.f, 0.f, 0.f};
    f32x4 st1 = (f32x4){0.f, 0.f, 0.f, 0.f};
    st0 = MFMA16x16x32(ka0, qf0, st0);
    st0 = MFMA16x16x32(ka1, qf1, st0);
    st1 = MFMA16x16x32(kb0, qf0, st1);
    st1 = MFMA16x16x32(kb1, qf1, st1);

    float s0[4], s1[4];
    float tmax = -1e30f;
#pragma unroll
    for (int r = 0; r < 4; ++r) {
      int keyA = kv0 + g * 8 + r;      // C-layout row -> key (tile0)
      int keyB = keyA + 4;             // tile1
      s0[r] = (keyA <= qrow) ? st0[r] * 0.125f : -1e30f;
      s1[r] = (keyB <= qrow) ? st1[r] * 0.125f : -1e30f;
      tmax = fmaxf(tmax, fmaxf(s0[r], s1[r]));
    }
    tmax = fmaxf(tmax, __shfl_xor(tmax, 16));
    tmax = fmaxf(tmax, __shfl_xor(tmax, 32));
    float mnew = fmaxf(mrow, tmax);
    float alpha = __expf(mrow - mnew);
    float tsum = 0.f;
    bf16x8 pb;
#pragma unroll
    for (int r = 0; r < 4; ++r) {
      float p0 = __expf(s0[r] - mnew);
      float p1 = __expf(s1[r] - mnew);
      tsum += p0 + p1;
      pb[r] = (short)f2bf(p0);
      pb[r + 4] = (short)f2bf(p1);
    }
    tsum += __shfl_xor(tsum, 16);
    tsum += __shfl_xor(tsum, 32);
    lsum = lsum * alpha + tsum;
    mrow = mnew;
#pragma unroll
    for (int d = 0; d < 4; ++d) {
      O[d][0] *= alpha; O[d][1] *= alpha; O[d][2] *= alpha; O[d][3] *= alpha;
    }
#pragma unroll
    for (int d = 0; d < 4; ++d) {
      bf16x8 vf;
      const unsigned short* vp = vb + (long)(kv0 + g * 8) * D3 + d * 16;
#pragma unroll
      for (int j = 0; j < 8; ++j) vf[j] = (short)vp[(long)j * D3];
      O[d] = MFMA16x16x32(vf, pb, O[d]);
    }
  }

  float inv = 1.0f / lsum;
  unsigned short* op = out + (long)(b * 2048 + qrow) * 1024 + h * 64;
#pragma unroll
  for (int d = 0; d < 4; ++d)
#pragma unroll
    for (int r = 0; r < 4; ++r)
      op[d * 16 + g * 4 + r] = f2bf(O[d][r] * inv);
}

extern "C" void kernel_launch(void* const* d_in, const int* in_sizes, int n_in,
                              void* d_out, int out_size, void* d_ws, size_t ws_size,
                              hipStream_t stream) {
  const float* x     = (const float*)d_in[0];
  const float* W_qkv = (const float*)d_in[1];
  const float* b_qkv = (const float*)d_in[2];
  const float* W_out = (const float*)d_in[3];
  const float* b_out = (const float*)d_in[4];

  char* ws = (char*)d_ws;
  unsigned short* xb    = (unsigned short*)ws;                  // 8 MB (x bf16; later reused as attn out)
  unsigned short* wqkvT = (unsigned short*)(ws + (8l << 20));   // 6 MB
  unsigned short* woutT = (unsigned short*)(ws + (14l << 20));  // 2 MB
  unsigned short* qkv   = (unsigned short*)(ws + (16l << 20));  // 24 MB

  conv_bf16<<<2048, 256, 0, stream>>>(x, xb, 524288);
  trans_f32_bf16<<<dim3(96, 32), dim3(32, 8), 0, stream>>>(W_qkv, wqkvT, 1024, 3072);
  trans_f32_bf16<<<dim3(32, 32), dim3(32, 8), 0, stream>>>(W_out, woutT, 1024, 1024);
  gemm_bt<1><<<dim3(24, 32), 256, 0, stream>>>(xb, wqkvT, b_qkv, (void*)qkv, 4096, 3072, 1024);
  attn_fwd<<<dim3(32, 128), 64, 0, stream>>>(qkv, xb);
  gemm_bt<0><<<dim3(8, 32), 256, 0, stream>>>(xb, woutT, b_out, d_out, 4096, 1024, 1024);
}

// Round 3
// 144.232 us; speedup vs baseline: 1.2959x; 1.2959x over previous
//
#include <hip/hip_runtime.h>

typedef short bf16x8 __attribute__((ext_vector_type(8)));
typedef short bf16x4 __attribute__((ext_vector_type(4)));
typedef short s16x4 __attribute__((ext_vector_type(4)));
typedef float f32x4 __attribute__((ext_vector_type(4)));
typedef unsigned short u16x8 __attribute__((ext_vector_type(8)));

#define MFMA16x16x32(a, b, c) __builtin_amdgcn_mfma_f32_16x16x32_bf16(a, b, c, 0, 0, 0)
#define TRR(dst, a) asm volatile("ds_read_b64_tr_b16 %0, %1" : "=v"(dst) : "v"(a))

__device__ __forceinline__ unsigned short f2bf(float f) {
  union { float f; unsigned u; } v; v.f = f;
  unsigned u = v.u + 0x7FFFu + ((v.u >> 16) & 1u);
  return (unsigned short)(u >> 16);
}

__device__ __forceinline__ void gload16(const void* g, void* l) {
  __builtin_amdgcn_global_load_lds((const __attribute__((address_space(1))) void*)g,
                                   (__attribute__((address_space(3))) void*)l, 16, 0, 0);
}

__device__ __forceinline__ unsigned ldsoff(const void* p) {
  return (unsigned)(unsigned long long)(const __attribute__((address_space(3))) void*)p;
}

// ---------------- fp32 -> bf16 elementwise (x) ----------------
__global__ __launch_bounds__(256) void conv_bf16(const float* __restrict__ in,
                                                 unsigned short* __restrict__ out, int n8) {
  int i = blockIdx.x * 256 + threadIdx.x;
  if (i >= n8) return;
  const float4* p = reinterpret_cast<const float4*>(in + (long)i * 8);
  float4 a = p[0], b = p[1];
  u16x8 o;
  o[0] = f2bf(a.x); o[1] = f2bf(a.y); o[2] = f2bf(a.z); o[3] = f2bf(a.w);
  o[4] = f2bf(b.x); o[5] = f2bf(b.y); o[6] = f2bf(b.z); o[7] = f2bf(b.w);
  *reinterpret_cast<u16x8*>(out + (long)i * 8) = o;
}

// ---------------- transpose + convert: W[K][N] f32 -> Wt[N][K] bf16 ----------------
__global__ __launch_bounds__(256) void trans_f32_bf16(const float* __restrict__ W,
                                                      unsigned short* __restrict__ Wt,
                                                      int K, int N) {
  __shared__ float tile[32][33];
  int n0 = blockIdx.x << 5, k0 = blockIdx.y << 5;
  int tx = threadIdx.x, ty = threadIdx.y;  // 32 x 8
#pragma unroll
  for (int i = 0; i < 32; i += 8)
    tile[ty + i][tx] = W[(long)(k0 + ty + i) * N + n0 + tx];
  __syncthreads();
#pragma unroll
  for (int i = 0; i < 32; i += 8)
    Wt[(long)(n0 + ty + i) * K + k0 + tx] = f2bf(tile[tx][ty + i]);
}

// ---------------- GEMM: C[M,N] = A[M,K] @ Bt[N,K]^T + bias, bf16 inputs ----------------
template <int BF16OUT>
__global__ __launch_bounds__(256) void gemm_bt(const unsigned short* __restrict__ A,
                                               const unsigned short* __restrict__ Bt,
                                               const float* __restrict__ bias,
                                               void* __restrict__ Cv,
                                               int M, int N, int K) {
  __shared__ __align__(128) unsigned short As[4096];  // [128][32]
  __shared__ __align__(128) unsigned short Bs[4096];  // [128][32]
  int t = threadIdx.x;
  int w = t >> 6, l = t & 63;
  int g = l >> 4, m16 = l & 15;
  int wr = w >> 1, wc = w & 1;
  long am0 = (long)blockIdx.y << 7;
  long bn0 = (long)blockIdx.x << 7;
  f32x4 acc[4][4];
#pragma unroll
  for (int i = 0; i < 4; ++i)
#pragma unroll
    for (int j = 0; j < 4; ++j) acc[i][j] = (f32x4){0.f, 0.f, 0.f, 0.f};

  for (int k0 = 0; k0 < K; k0 += 32) {
#pragma unroll
    for (int i = 0; i < 2; ++i) {
      int seg = i * 4 + w;
      int flat = (seg << 9) + (l << 3);
      int r_ = flat >> 5, c_ = flat & 31;
      gload16(A + (am0 + r_) * K + k0 + c_, &As[seg << 9]);
      gload16(Bt + (bn0 + r_) * K + k0 + c_, &Bs[seg << 9]);
    }
    __syncthreads();
    bf16x8 af[4], bfr[4];
#pragma unroll
    for (int im = 0; im < 4; ++im)
      af[im] = *(const bf16x8*)&As[((wr << 6) + (im << 4) + m16) * 32 + (g << 3)];
#pragma unroll
    for (int in = 0; in < 4; ++in)
      bfr[in] = *(const bf16x8*)&Bs[((wc << 6) + (in << 4) + m16) * 32 + (g << 3)];
    __builtin_amdgcn_s_setprio(1);
#pragma unroll
    for (int im = 0; im < 4; ++im)
#pragma unroll
      for (int in = 0; in < 4; ++in)
        acc[im][in] = MFMA16x16x32(af[im], bfr[in], acc[im][in]);
    __builtin_amdgcn_s_setprio(0);
    __syncthreads();
  }

#pragma unroll
  for (int im = 0; im < 4; ++im) {
#pragma unroll
    for (int in = 0; in < 4; ++in) {
      long col = bn0 + (wc << 6) + (in << 4) + m16;
      float bval = bias[col];
#pragma unroll
      for (int r = 0; r < 4; ++r) {
        long row = am0 + (wr << 6) + (im << 4) + (g << 2) + r;
        float v = acc[im][in][r] + bval;
        if (BF16OUT)
          ((unsigned short*)Cv)[row * N + col] = f2bf(v);
        else
          ((float*)Cv)[row * N + col] = v;
      }
    }
  }
}

// ---------------- causal flash attention (4-wave blocks, LDS-staged K/V) ----------------
// qkv: bf16 [B*S][3072]; out: bf16 [B*S][1024].
// grid: (B*H=32, 32), block 256. Each wave owns 16 q rows; block owns 64.
// K tile [32 rows][64 d] in LDS, XOR-swizzled 16B chunks (chunk ^= row&7), staged via
// global_load_lds with pre-swizzled per-lane source (rule 21).
// V tile as 32 subtiles [db 4][kb 8][4 key][16 d] (128B each) for ds_read_b64_tr_b16.
// tr_b16 semantics (m156/m162): block = addr & ~127; column = (addr&127)>>3;
// elem j = block + 2*column + 32*j bytes. Lane (g,m16) passes addr = block(g)*128 + m16*8
// -> reads V[kb*4 + j][db*16 + m16] for j=0..3 = the PV A-fragment column.
__global__ __launch_bounds__(256) void attn_fwd(const unsigned short* __restrict__ qkv,
                                                unsigned short* __restrict__ out) {
  const int D3 = 3072;
  __shared__ __align__(128) unsigned short Ks[2][2048];
  __shared__ __align__(128) unsigned short Vs[2][2048];
  int b = blockIdx.x >> 4, h = blockIdx.x & 15;
  int yy = blockIdx.y;
  int qt = (yy & 1) ? (31 - (yy >> 1)) : (yy >> 1);  // heavy/light interleave
  int q0 = qt << 6;
  int t = threadIdx.x;
  int w = t >> 6, l = t & 63;
  int g = l >> 4, m16 = l & 15;
  int q0w = q0 + (w << 4);
  int qrow = q0w + m16;
  long base = (long)b * 2048 * D3;

  const unsigned short* kbase = qkv + base + 1024 + h * 64;
  const unsigned short* vbase = qkv + base + 2048 + h * 64;

  // per-lane staging offsets (loop-invariant). Each wave stages 64 16B chunks of K and V.
  int sr = (w << 3) + (l >> 3);  // K row / V subtile index 0..31
  int sc = l & 7;                // 16B chunk within 128B row/subtile
  int koff = sr * D3 + ((sc ^ (sr & 7)) << 3);
  int vdb = sr >> 3, vkb = sr & 7;
  int vkk = sc >> 1, vd8 = sc & 1;
  int voff = (vkb * 4 + vkk) * D3 + (vdb << 4) + (vd8 << 3);

  // Q fragments (held in registers for the whole kernel)
  const unsigned short* qp = qkv + base + (long)qrow * D3 + h * 64;
  bf16x8 qf0 = *(const bf16x8*)(qp + g * 8);
  bf16x8 qf1 = *(const bf16x8*)(qp + 32 + g * 8);

  f32x4 O[4];
#pragma unroll
  for (int d = 0; d < 4; ++d) O[d] = (f32x4){0.f, 0.f, 0.f, 0.f};
  float mrow = -1e30f, lsum = 0.f;

  int nt = (q0 + 64) >> 5;
  gload16(kbase + koff, &Ks[0][w << 9]);
  gload16(vbase + voff, &Vs[0][w << 9]);
  __syncthreads();

  int buf = 0;
  for (int it = 0; it < nt; ++it) {
    int kv0 = it << 5;
    if (it + 1 < nt) {
      const unsigned short* kt = kbase + (long)(kv0 + 32) * D3;
      const unsigned short* vt = vbase + (long)(kv0 + 32) * D3;
      gload16(kt + koff, &Ks[buf ^ 1][w << 9]);
      gload16(vt + voff, &Vs[buf ^ 1][w << 9]);
    }
    if (kv0 < q0w + 16) {  // wave-active (has at least one unmasked key)
      // issue V transpose-reads early (latency hides under QK^T + softmax)
      unsigned va = ldsoff(&Vs[buf][0]) + (g << 7) + (m16 << 3);
      bf16x4 tA0, tB0, tA1, tB1, tA2, tB2, tA3, tB3;
      TRR(tA0, va);          TRR(tB0, va + 512);
      TRR(tA1, va + 1024);   TRR(tB1, va + 1536);
      TRR(tA2, va + 2048);   TRR(tB2, va + 2560);
      TRR(tA3, va + 3072);   TRR(tB3, va + 3584);

      // K fragments from swizzled LDS tile
      const char* kbuf = (const char*)&Ks[buf][0];
      int sw = (m16 & 7) << 4;
      bf16x8 ka0 = *(const bf16x8*)(kbuf + (m16 << 7) + ((g << 4) ^ sw));
      bf16x8 ka1 = *(const bf16x8*)(kbuf + (m16 << 7) + (((4 + g) << 4) ^ sw));
      bf16x8 kc0 = *(const bf16x8*)(kbuf + ((16 + m16) << 7) + ((g << 4) ^ sw));
      bf16x8 kc1 = *(const bf16x8*)(kbuf + ((16 + m16) << 7) + (((4 + g) << 4) ^ sw));

      f32x4 st0 = (f32x4){0.f, 0.f, 0.f, 0.f};
      f32x4 st1 = (f32x4){0.f, 0.f, 0.f, 0.f};
      __builtin_amdgcn_s_setprio(1);
      st0 = MFMA16x16x32(ka0, qf0, st0);
      st0 = MFMA16x16x32(ka1, qf1, st0);
      st1 = MFMA16x16x32(kc0, qf0, st1);
      st1 = MFMA16x16x32(kc1, qf1, st1);
      __builtin_amdgcn_s_setprio(0);

      // online softmax; C-layout: col=q=m16, row=key: st0 row g*4+r -> key kv0+g*4+r,
      // st1 -> key kv0+16+g*4+r
      float s0[4], s1[4];
      float tmax = -1e30f;
      bool full = (kv0 + 31) <= q0w;  // wave-uniform: no masking needed
      if (full) {
#pragma unroll
        for (int r = 0; r < 4; ++r) {
          s0[r] = st0[r] * 0.125f;
          s1[r] = st1[r] * 0.125f;
          tmax = fmaxf(tmax, fmaxf(s0[r], s1[r]));
        }
      } else {
#pragma unroll
        for (int r = 0; r < 4; ++r) {
          int keyA = kv0 + (g << 2) + r;
          int keyB = keyA + 16;
          s0[r] = (keyA <= qrow) ? st0[r] * 0.125f : -1e30f;
          s1[r] = (keyB <= qrow) ? st1[r] * 0.125f : -1e30f;
          tmax = fmaxf(tmax, fmaxf(s0[r], s1[r]));
        }
      }
      tmax = fmaxf(tmax, __shfl_xor(tmax, 16));
      tmax = fmaxf(tmax, __shfl_xor(tmax, 32));
      float mnew = fmaxf(mrow, tmax);
      float alpha = __expf(mrow - mnew);
      float tsum = 0.f;
      bf16x8 pb;
#pragma unroll
      for (int r = 0; r < 4; ++r) {
        float p0 = __expf(s0[r] - mnew);
        float p1 = __expf(s1[r] - mnew);
        tsum += p0 + p1;
        pb[r] = (short)f2bf(p0);
        pb[r + 4] = (short)f2bf(p1);
      }
      tsum += __shfl_xor(tsum, 16);
      tsum += __shfl_xor(tsum, 32);
      lsum = lsum * alpha + tsum;
      mrow = mnew;
#pragma unroll
      for (int d = 0; d < 4; ++d) {
        O[d][0] *= alpha; O[d][1] *= alpha; O[d][2] *= alpha; O[d][3] *= alpha;
      }

      // fence: inline-asm ds_reads complete + keep dependent ops below (rule 18)
      asm volatile("s_waitcnt lgkmcnt(0)" ::: "memory");
      __builtin_amdgcn_sched_barrier(0);

      bf16x8 vf0 = __builtin_shufflevector(tA0, tB0, 0, 1, 2, 3, 4, 5, 6, 7);
      bf16x8 vf1 = __builtin_shufflevector(tA1, tB1, 0, 1, 2, 3, 4, 5, 6, 7);
      bf16x8 vf2 = __builtin_shufflevector(tA2, tB2, 0, 1, 2, 3, 4, 5, 6, 7);
      bf16x8 vf3 = __builtin_shufflevector(tA3, tB3, 0, 1, 2, 3, 4, 5, 6, 7);
      __builtin_amdgcn_s_setprio(1);
      O[0] = MFMA16x16x32(vf0, pb, O[0]);
      O[1] = MFMA16x16x32(vf1, pb, O[1]);
      O[2] = MFMA16x16x32(vf2, pb, O[2]);
      O[3] = MFMA16x16x32(vf3, pb, O[3]);
      __builtin_amdgcn_s_setprio(0);
    }
    __syncthreads();
    buf ^= 1;
  }

  float inv = 1.0f / lsum;
  unsigned short* op = out + (long)(b * 2048 + qrow) * 1024 + h * 64;
#pragma unroll
  for (int d = 0; d < 4; ++d) {
    s16x4 pk;
#pragma unroll
    for (int r = 0; r < 4; ++r) pk[r] = (short)f2bf(O[d][r] * inv);
    *reinterpret_cast<s16x4*>(op + (d << 4) + (g << 2)) = pk;
  }
}

extern "C" void kernel_launch(void* const* d_in, const int* in_sizes, int n_in,
                              void* d_out, int out_size, void* d_ws, size_t ws_size,
                              hipStream_t stream) {
  const float* x     = (const float*)d_in[0];
  const float* W_qkv = (const float*)d_in[1];
  const float* b_qkv = (const float*)d_in[2];
  const float* W_out = (const float*)d_in[3];
  const float* b_out = (const float*)d_in[4];

  char* ws = (char*)d_ws;
  unsigned short* xb    = (unsigned short*)ws;                  // 8 MB (x bf16; reused as attn out)
  unsigned short* wqkvT = (unsigned short*)(ws + (8l << 20));   // 6 MB
  unsigned short* woutT = (unsigned short*)(ws + (14l << 20));  // 2 MB
  unsigned short* qkv   = (unsigned short*)(ws + (16l << 20));  // 24 MB

  conv_bf16<<<2048, 256, 0, stream>>>(x, xb, 524288);
  trans_f32_bf16<<<dim3(96, 32), dim3(32, 8), 0, stream>>>(W_qkv, wqkvT, 1024, 3072);
  trans_f32_bf16<<<dim3(32, 32), dim3(32, 8), 0, stream>>>(W_out, woutT, 1024, 1024);
  gemm_bt<1><<<dim3(24, 32), 256, 0, stream>>>(xb, wqkvT, b_qkv, (void*)qkv, 4096, 3072, 1024);
  attn_fwd<<<dim3(32, 32), 256, 0, stream>>>(qkv, xb);
  gemm_bt<0><<<dim3(8, 32), 256, 0, stream>>>(xb, woutT, b_out, d_out, 4096, 1024, 1024);
}

// Round 5
// 127.418 us; speedup vs baseline: 1.4669x; 1.1320x over previous
//
#include <hip/hip_runtime.h>

typedef short bf16x8 __attribute__((ext_vector_type(8)));
typedef short bf16x4 __attribute__((ext_vector_type(4)));
typedef short s16x4 __attribute__((ext_vector_type(4)));
typedef float f32x4 __attribute__((ext_vector_type(4)));
typedef unsigned short u16x8 __attribute__((ext_vector_type(8)));

#define MFMA16x16x32(a, b, c) __builtin_amdgcn_mfma_f32_16x16x32_bf16(a, b, c, 0, 0, 0)
#define TRR(dst, a) asm volatile("ds_read_b64_tr_b16 %0, %1" : "=v"(dst) : "v"(a))

__device__ __forceinline__ unsigned short f2bf(float f) {
  union { float f; unsigned u; } v; v.f = f;
  unsigned u = v.u + 0x7FFFu + ((v.u >> 16) & 1u);
  return (unsigned short)(u >> 16);
}

__device__ __forceinline__ void gload16(const void* g, void* l) {
  __builtin_amdgcn_global_load_lds((const __attribute__((address_space(1))) void*)g,
                                   (__attribute__((address_space(3))) void*)l, 16, 0, 0);
}

__device__ __forceinline__ unsigned ldsoff(const void* p) {
  return (unsigned)(unsigned long long)(const __attribute__((address_space(3))) void*)p;
}

// ---------------- fp32 -> bf16 elementwise (x) ----------------
__global__ __launch_bounds__(256) void conv_bf16(const float* __restrict__ in,
                                                 unsigned short* __restrict__ out, int n8) {
  int i = blockIdx.x * 256 + threadIdx.x;
  if (i >= n8) return;
  const float4* p = reinterpret_cast<const float4*>(in + (long)i * 8);
  float4 a = p[0], b = p[1];
  u16x8 o;
  o[0] = f2bf(a.x); o[1] = f2bf(a.y); o[2] = f2bf(a.z); o[3] = f2bf(a.w);
  o[4] = f2bf(b.x); o[5] = f2bf(b.y); o[6] = f2bf(b.z); o[7] = f2bf(b.w);
  *reinterpret_cast<u16x8*>(out + (long)i * 8) = o;
}

// ---------------- transpose + convert: W[K][N] f32 -> Wt[N][K] bf16 ----------------
__global__ __launch_bounds__(256) void trans_f32_bf16(const float* __restrict__ W,
                                                      unsigned short* __restrict__ Wt,
                                                      int K, int N) {
  __shared__ float tile[32][33];
  int n0 = blockIdx.x << 5, k0 = blockIdx.y << 5;
  int tx = threadIdx.x, ty = threadIdx.y;  // 32 x 8
#pragma unroll
  for (int i = 0; i < 32; i += 8)
    tile[ty + i][tx] = W[(long)(k0 + ty + i) * N + n0 + tx];
  __syncthreads();
#pragma unroll
  for (int i = 0; i < 32; i += 8)
    Wt[(long)(n0 + ty + i) * K + k0 + tx] = f2bf(tile[tx][ty + i]);
}

// ---------------- GEMM: C[M,N] = A[M,K] @ Bt[N,K]^T + bias, bf16 inputs ----------------
template <int BF16OUT>
__global__ __launch_bounds__(256) void gemm_bt(const unsigned short* __restrict__ A,
                                               const unsigned short* __restrict__ Bt,
                                               const float* __restrict__ bias,
                                               void* __restrict__ Cv,
                                               int M, int N, int K) {
  __shared__ __align__(128) unsigned short As[4096];  // [128][32]
  __shared__ __align__(128) unsigned short Bs[4096];  // [128][32]
  int t = threadIdx.x;
  int w = t >> 6, l = t & 63;
  int g = l >> 4, m16 = l & 15;
  int wr = w >> 1, wc = w & 1;
  long am0 = (long)blockIdx.y << 7;
  long bn0 = (long)blockIdx.x << 7;
  f32x4 acc[4][4];
#pragma unroll
  for (int i = 0; i < 4; ++i)
#pragma unroll
    for (int j = 0; j < 4; ++j) acc[i][j] = (f32x4){0.f, 0.f, 0.f, 0.f};

  for (int k0 = 0; k0 < K; k0 += 32) {
#pragma unroll
    for (int i = 0; i < 2; ++i) {
      int seg = i * 4 + w;
      int flat = (seg << 9) + (l << 3);
      int r_ = flat >> 5, c_ = flat & 31;
      gload16(A + (am0 + r_) * K + k0 + c_, &As[seg << 9]);
      gload16(Bt + (bn0 + r_) * K + k0 + c_, &Bs[seg << 9]);
    }
    __syncthreads();
    bf16x8 af[4], bfr[4];
#pragma unroll
    for (int im = 0; im < 4; ++im)
      af[im] = *(const bf16x8*)&As[((wr << 6) + (im << 4) + m16) * 32 + (g << 3)];
#pragma unroll
    for (int in = 0; in < 4; ++in)
      bfr[in] = *(const bf16x8*)&Bs[((wc << 6) + (in << 4) + m16) * 32 + (g << 3)];
    __builtin_amdgcn_s_setprio(1);
#pragma unroll
    for (int im = 0; im < 4; ++im)
#pragma unroll
      for (int in = 0; in < 4; ++in)
        acc[im][in] = MFMA16x16x32(af[im], bfr[in], acc[im][in]);
    __builtin_amdgcn_s_setprio(0);
    __syncthreads();
  }

#pragma unroll
  for (int im = 0; im < 4; ++im) {
#pragma unroll
    for (int in = 0; in < 4; ++in) {
      long col = bn0 + (wc << 6) + (in << 4) + m16;
      float bval = bias[col];
#pragma unroll
      for (int r = 0; r < 4; ++r) {
        long row = am0 + (wr << 6) + (im << 4) + (g << 2) + r;
        float v = acc[im][in][r] + bval;
        if (BF16OUT)
          ((unsigned short*)Cv)[row * N + col] = f2bf(v);
        else
          ((float*)Cv)[row * N + col] = v;
      }
    }
  }
}

// ---------------- causal flash attention (4-wave blocks, KVBLK=64) ----------------
// qkv: bf16 [B*S][3072]; out: bf16 [B*S][1024].
// grid: (B*H=32, 32), block 256. Each wave owns 16 q rows; block owns 64.
// K tile [64 rows][64 d] in LDS (8KB), XOR-swizzled 16B chunks (chunk ^= row&7).
// V tile as 64 subtiles [db 4][kb 16][4 key][16 d] (128B each, 8KB) for tr_b16 reads:
// block = addr & ~127; column = (addr&127)>>3; elem j at block + 2*col + 32*j bytes.
// With KVBLK=64, every wave is active in every tile; nt = qt+1; only the last
// (diagonal) tile needs masking.
__global__ __launch_bounds__(256) void attn_fwd(const unsigned short* __restrict__ qkv,
                                                unsigned short* __restrict__ out) {
  const int D3 = 3072;
  __shared__ __align__(128) unsigned short Ks[2][4096];
  __shared__ __align__(128) unsigned short Vs[2][4096];
  int b = blockIdx.x >> 4, h = blockIdx.x & 15;
  int yy = blockIdx.y;
  int qt = (yy & 1) ? (31 - (yy >> 1)) : (yy >> 1);  // heavy blocks early
  int q0 = qt << 6;
  int t = threadIdx.x;
  int w = t >> 6, l = t & 63;
  int g = l >> 4, m16 = l & 15;
  int qrow = q0 + (w << 4) + m16;
  long base = (long)b * 2048 * D3;
  const unsigned short* kbase = qkv + base + 1024 + h * 64;
  const unsigned short* vbase = qkv + base + 2048 + h * 64;

  // staging offsets (loop-invariant): each thread stages 2 K chunks + 2 V chunks.
  int l8 = l >> 3, sc = l & 7;
  int kof = (w * 8 + l8) * D3 + ((sc ^ l8) << 3);
  int s0 = w * 8 + l8;  // subtile: db = s>>4, kb = s&15; i=1 is +32 elems (db+2)
  int vof = ((s0 & 15) * 4 + (sc >> 1)) * D3 + ((s0 >> 4) << 4) + ((sc & 1) << 3);

  const unsigned short* qp = qkv + base + (long)qrow * D3 + h * 64;
  bf16x8 qf0 = *(const bf16x8*)(qp + g * 8);
  bf16x8 qf1 = *(const bf16x8*)(qp + 32 + g * 8);

  const f32x4 zero4 = (f32x4){0.f, 0.f, 0.f, 0.f};
  f32x4 O[4];
#pragma unroll
  for (int d = 0; d < 4; ++d) O[d] = zero4;
  float mrow = -1e30f, lsum = 0.f;
  int nt = qt + 1;

  gload16(kbase + kof, &Ks[0][w << 9]);
  gload16(kbase + 32 * D3 + kof, &Ks[0][2048 + (w << 9)]);
  gload16(vbase + vof, &Vs[0][w << 9]);
  gload16(vbase + vof + 32, &Vs[0][2048 + (w << 9)]);
  __syncthreads();

  int buf = 0;
  for (int it = 0; it < nt; ++it) {
    if (it + 1 < nt) {
      long off = (long)(it + 1) * 64 * D3;
      gload16(kbase + off + kof, &Ks[buf ^ 1][w << 9]);
      gload16(kbase + off + 32 * D3 + kof, &Ks[buf ^ 1][2048 + (w << 9)]);
      gload16(vbase + off + vof, &Vs[buf ^ 1][w << 9]);
      gload16(vbase + off + vof + 32, &Vs[buf ^ 1][2048 + (w << 9)]);
    }
    // V transpose-reads issued early; latency hides under QK^T + softmax.
    unsigned va = ldsoff(&Vs[buf][0]) + (g << 7) + (m16 << 3);
    bf16x4 t0[4], t1[4], t2[4], t3[4];
#pragma unroll
    for (int d = 0; d < 4; ++d) {
      unsigned a = va + (d << 11);
      TRR(t0[d], a);          // kb = g      -> keys 4g..4g+3
      TRR(t1[d], a + 512);    // kb = g+4    -> keys 16+4g..
      TRR(t2[d], a + 1024);   // kb = 8+g    -> keys 32+4g..
      TRR(t3[d], a + 1536);   // kb = 12+g   -> keys 48+4g..
    }
    // K fragments (swizzled) + QK^T
    const char* kbuf = (const char*)&Ks[buf][0];
    int swz = m16 & 7;
    bf16x8 kf0[4], kf1[4];
#pragma unroll
    for (int T = 0; T < 4; ++T) {
      const char* rp = kbuf + (((T << 4) + m16) << 7);
      kf0[T] = *(const bf16x8*)(rp + ((g ^ swz) << 4));
      kf1[T] = *(const bf16x8*)(rp + (((4 + g) ^ swz) << 4));
    }
    f32x4 st[4];
    __builtin_amdgcn_s_setprio(1);
#pragma unroll
    for (int T = 0; T < 4; ++T) {
      st[T] = MFMA16x16x32(kf0[T], qf0, zero4);
      st[T] = MFMA16x16x32(kf1[T], qf1, st[T]);
    }
    __builtin_amdgcn_s_setprio(0);

    // C layout: col = q = m16, row(T, g, r) -> key = it*64 + T*16 + g*4 + r
    if (it == nt - 1) {  // diagonal tile: mask (wave-uniform branch)
      int rq = (w << 4) + m16;
#pragma unroll
      for (int T = 0; T < 4; ++T)
#pragma unroll
        for (int r = 0; r < 4; ++r)
          if ((T << 4) + (g << 2) + r > rq) st[T][r] = -3e38f;
    }
    float tmax = st[0][0];
#pragma unroll
    for (int T = 0; T < 4; ++T)
#pragma unroll
      for (int r = 0; r < 4; ++r) tmax = fmaxf(tmax, st[T][r]);
    tmax = fmaxf(tmax, __shfl_xor(tmax, 16));
    tmax = fmaxf(tmax, __shfl_xor(tmax, 32));
    float tsc = tmax * 0.125f;
    bool skip = __all(tsc <= mrow + 8.0f);  // defer-max (T13)
    float mnew = skip ? mrow : fmaxf(mrow, tsc);
    float p[4][4];
    float tsum = 0.f;
#pragma unroll
    for (int T = 0; T < 4; ++T)
#pragma unroll
      for (int r = 0; r < 4; ++r) {
        float e = __expf(fmaf(st[T][r], 0.125f, -mnew));
        p[T][r] = e;
        tsum += e;
      }
    tsum += __shfl_xor(tsum, 16);
    tsum += __shfl_xor(tsum, 32);
    if (!skip) {
      float alpha = __expf(mrow - mnew);
      lsum *= alpha;
#pragma unroll
      for (int d = 0; d < 4; ++d) {
        O[d][0] *= alpha; O[d][1] *= alpha; O[d][2] *= alpha; O[d][3] *= alpha;
      }
      mrow = mnew;
    }
    lsum += tsum;

    bf16x8 pb0, pb1;
#pragma unroll
    for (int r = 0; r < 4; ++r) {
      pb0[r] = (short)f2bf(p[0][r]); pb0[r + 4] = (short)f2bf(p[1][r]);
      pb1[r] = (short)f2bf(p[2][r]); pb1[r + 4] = (short)f2bf(p[3][r]);
    }

    asm volatile("s_waitcnt lgkmcnt(0)" ::: "memory");
    __builtin_amdgcn_sched_barrier(0);

    bf16x8 vfA[4], vfB[4];
#pragma unroll
    for (int d = 0; d < 4; ++d) {
      vfA[d] = __builtin_shufflevector(t0[d], t1[d], 0, 1, 2, 3, 4, 5, 6, 7);
      vfB[d] = __builtin_shufflevector(t2[d], t3[d], 0, 1, 2, 3, 4, 5, 6, 7);
    }
    __builtin_amdgcn_s_setprio(1);
#pragma unroll
    for (int d = 0; d < 4; ++d) {
      O[d] = MFMA16x16x32(vfA[d], pb0, O[d]);
      O[d] = MFMA16x16x32(vfB[d], pb1, O[d]);
    }
    __builtin_amdgcn_s_setprio(0);
    __syncthreads();
    buf ^= 1;
  }

  float inv = 1.0f / lsum;
  unsigned short* op = out + (long)(b * 2048 + qrow) * 1024 + h * 64;
#pragma unroll
  for (int d = 0; d < 4; ++d) {
    s16x4 pk;
#pragma unroll
    for (int r = 0; r < 4; ++r) pk[r] = (short)f2bf(O[d][r] * inv);
    *reinterpret_cast<s16x4*>(op + (d << 4) + (g << 2)) = pk;
  }
}

extern "C" void kernel_launch(void* const* d_in, const int* in_sizes, int n_in,
                              void* d_out, int out_size, void* d_ws, size_t ws_size,
                              hipStream_t stream) {
  const float* x     = (const float*)d_in[0];
  const float* W_qkv = (const float*)d_in[1];
  const float* b_qkv = (const float*)d_in[2];
  const float* W_out = (const float*)d_in[3];
  const float* b_out = (const float*)d_in[4];

  char* ws = (char*)d_ws;
  unsigned short* xb    = (unsigned short*)ws;                  // 8 MB (x bf16; reused as attn out)
  unsigned short* wqkvT = (unsigned short*)(ws + (8l << 20));   // 6 MB
  unsigned short* woutT = (unsigned short*)(ws + (14l << 20));  // 2 MB
  unsigned short* qkv   = (unsigned short*)(ws + (16l << 20));  // 24 MB

  conv_bf16<<<2048, 256, 0, stream>>>(x, xb, 524288);
  trans_f32_bf16<<<dim3(96, 32), dim3(32, 8), 0, stream>>>(W_qkv, wqkvT, 1024, 3072);
  trans_f32_bf16<<<dim3(32, 32), dim3(32, 8), 0, stream>>>(W_out, woutT, 1024, 1024);
  gemm_bt<1><<<dim3(24, 32), 256, 0, stream>>>(xb, wqkvT, b_qkv, (void*)qkv, 4096, 3072, 1024);
  attn_fwd<<<dim3(32, 32), 256, 0, stream>>>(qkv, xb);
  gemm_bt<0><<<dim3(8, 32), 256, 0, stream>>>(xb, woutT, b_out, d_out, 4096, 1024, 1024);
}

// Round 6
// 118.990 us; speedup vs baseline: 1.5708x; 1.0708x over previous
//
#include <hip/hip_runtime.h>

typedef short bf16x8 __attribute__((ext_vector_type(8)));
typedef short bf16x4 __attribute__((ext_vector_type(4)));
typedef float f32x4 __attribute__((ext_vector_type(4)));
typedef int i32x4 __attribute__((ext_vector_type(4)));
typedef int i32x2 __attribute__((ext_vector_type(2)));

#define MFMA16x16x32(a, b, c) __builtin_amdgcn_mfma_f32_16x16x32_bf16(a, b, c, 0, 0, 0)
#define TRR(dst, a) asm volatile("ds_read_b64_tr_b16 %0, %1" : "=v"(dst) : "v"(a))

__device__ __forceinline__ unsigned short f2bf(float f) {
  union { float f; unsigned u; } v; v.f = f;
  unsigned u = v.u + 0x7FFFu + ((v.u >> 16) & 1u);
  return (unsigned short)(u >> 16);
}

__device__ __forceinline__ unsigned cvtpk(float lo, float hi) {
  unsigned r;
  asm("v_cvt_pk_bf16_f32 %0, %1, %2" : "=v"(r) : "v"(lo), "v"(hi));
  return r;
}

__device__ __forceinline__ float max3f(float a, float b, float c) {
  float d;
  asm("v_max3_f32 %0, %1, %2, %3" : "=v"(d) : "v"(a), "v"(b), "v"(c));
  return d;
}

__device__ __forceinline__ void gload16(const void* g, void* l) {
  __builtin_amdgcn_global_load_lds((const __attribute__((address_space(1))) void*)g,
                                   (__attribute__((address_space(3))) void*)l, 16, 0, 0);
}

__device__ __forceinline__ unsigned ldsoff(const void* p) {
  return (unsigned)(unsigned long long)(const __attribute__((address_space(3))) void*)p;
}

// ---------------- fp32 -> bf16 elementwise (x) ----------------
__global__ __launch_bounds__(256) void conv_bf16(const float* __restrict__ in,
                                                 unsigned short* __restrict__ out, int n8) {
  int i = blockIdx.x * 256 + threadIdx.x;
  if (i >= n8) return;
  const float4* p = reinterpret_cast<const float4*>(in + (long)i * 8);
  float4 a = p[0], b = p[1];
  i32x4 o;
  o[0] = cvtpk(a.x, a.y); o[1] = cvtpk(a.z, a.w);
  o[2] = cvtpk(b.x, b.y); o[3] = cvtpk(b.z, b.w);
  *reinterpret_cast<i32x4*>(out + (long)i * 8) = o;
}

// ---------------- transpose + convert: W[K][N] f32 -> Wt[N][K] bf16 ----------------
__global__ __launch_bounds__(256) void trans_f32_bf16(const float* __restrict__ W,
                                                      unsigned short* __restrict__ Wt,
                                                      int K, int N) {
  __shared__ float tile[32][33];
  int n0 = blockIdx.x << 5, k0 = blockIdx.y << 5;
  int tx = threadIdx.x, ty = threadIdx.y;  // 32 x 8
#pragma unroll
  for (int i = 0; i < 32; i += 8)
    tile[ty + i][tx] = W[(long)(k0 + ty + i) * N + n0 + tx];
  __syncthreads();
#pragma unroll
  for (int i = 0; i < 32; i += 8)
    Wt[(long)(n0 + ty + i) * K + k0 + tx] = f2bf(tile[tx][ty + i]);
}

// ---------------- GEMM: C[M,N] = A[M,K] @ Bt[N,K]^T + bias, bf16 inputs ----------------
template <int BF16OUT>
__global__ __launch_bounds__(256) void gemm_bt(const unsigned short* __restrict__ A,
                                               const unsigned short* __restrict__ Bt,
                                               const float* __restrict__ bias,
                                               void* __restrict__ Cv,
                                               int M, int N, int K) {
  __shared__ __align__(128) unsigned short As[4096];  // [128][32]
  __shared__ __align__(128) unsigned short Bs[4096];  // [128][32]
  int t = threadIdx.x;
  int w = t >> 6, l = t & 63;
  int g = l >> 4, m16 = l & 15;
  int wr = w >> 1, wc = w & 1;
  long am0 = (long)blockIdx.y << 7;
  long bn0 = (long)blockIdx.x << 7;
  f32x4 acc[4][4];
#pragma unroll
  for (int i = 0; i < 4; ++i)
#pragma unroll
    for (int j = 0; j < 4; ++j) acc[i][j] = (f32x4){0.f, 0.f, 0.f, 0.f};

  for (int k0 = 0; k0 < K; k0 += 32) {
#pragma unroll
    for (int i = 0; i < 2; ++i) {
      int seg = i * 4 + w;
      int flat = (seg << 9) + (l << 3);
      int r_ = flat >> 5, c_ = flat & 31;
      gload16(A + (am0 + r_) * K + k0 + c_, &As[seg << 9]);
      gload16(Bt + (bn0 + r_) * K + k0 + c_, &Bs[seg << 9]);
    }
    __syncthreads();
    bf16x8 af[4], bfr[4];
#pragma unroll
    for (int im = 0; im < 4; ++im)
      af[im] = *(const bf16x8*)&As[((wr << 6) + (im << 4) + m16) * 32 + (g << 3)];
#pragma unroll
    for (int in = 0; in < 4; ++in)
      bfr[in] = *(const bf16x8*)&Bs[((wc << 6) + (in << 4) + m16) * 32 + (g << 3)];
    __builtin_amdgcn_s_setprio(1);
#pragma unroll
    for (int im = 0; im < 4; ++im)
#pragma unroll
      for (int in = 0; in < 4; ++in)
        acc[im][in] = MFMA16x16x32(af[im], bfr[in], acc[im][in]);
    __builtin_amdgcn_s_setprio(0);
    __syncthreads();
  }

#pragma unroll
  for (int im = 0; im < 4; ++im) {
#pragma unroll
    for (int in = 0; in < 4; ++in) {
      long col = bn0 + (wc << 6) + (in << 4) + m16;
      float bval = bias[col];
#pragma unroll
      for (int r = 0; r < 4; ++r) {
        long row = am0 + (wr << 6) + (im << 4) + (g << 2) + r;
        float v = acc[im][in][r] + bval;
        if (BF16OUT)
          ((unsigned short*)Cv)[row * N + col] = f2bf(v);
        else
          ((float*)Cv)[row * N + col] = v;
      }
    }
  }
}

// ---------------- causal flash attention (4-wave blocks, KVBLK=64, paired q-tiles) ----
// grid: (B*H=32, 16), block 256. Block y handles q-tiles {y, 31-y} sequentially ->
// every block does exactly (y+1)+(32-y) = 33 tile-iterations: perfect balance.
// K tile [64][64] LDS, XOR-swizzled 16B chunks; V tile as 64 [4key][16d] subtiles
// for ds_read_b64_tr_b16 (block=addr&~127, col=(addr&127)>>3, elem j at +32j bytes).
// Softmax in log2-domain: m2 = m*log2e; p = exp2(st*C1 - m2); defer-max (T13) THR=8.
__global__ __launch_bounds__(256) void attn_fwd(const unsigned short* __restrict__ qkv,
                                                unsigned short* __restrict__ out) {
  const int D3 = 3072;
  const float C1 = 0.18033688f;    // 0.125 * log2(e)
  const float THR = 11.5415603f;   // 8 * log2(e)
  __shared__ __align__(128) unsigned short Ks[2][4096];
  __shared__ __align__(128) unsigned short Vs[2][4096];
  int b = blockIdx.x >> 4, h = blockIdx.x & 15;
  int t = threadIdx.x;
  int w = t >> 6, l = t & 63;
  int g = l >> 4, m16 = l & 15;
  long base = (long)b * 2048 * D3;
  const unsigned short* kbase = qkv + base + 1024 + h * 64;
  const unsigned short* vbase = qkv + base + 2048 + h * 64;

  // staging offsets (loop-invariant): each thread stages 2 K chunks + 2 V chunks.
  int l8 = l >> 3, sc = l & 7;
  int kof = (w * 8 + l8) * D3 + ((sc ^ l8) << 3);
  int s0 = w * 8 + l8;
  int vof = ((s0 & 15) * 4 + (sc >> 1)) * D3 + ((s0 >> 4) << 4) + ((sc & 1) << 3);
  const f32x4 zero4 = (f32x4){0.f, 0.f, 0.f, 0.f};

  for (int sgi = 0; sgi < 2; ++sgi) {
    int qt = sgi ? (31 - blockIdx.y) : blockIdx.y;
    int q0 = qt << 6;
    int qrow = q0 + (w << 4) + m16;
    const unsigned short* qp = qkv + base + (long)qrow * D3 + h * 64;
    bf16x8 qf0 = *(const bf16x8*)(qp + g * 8);
    bf16x8 qf1 = *(const bf16x8*)(qp + 32 + g * 8);

    f32x4 O[4];
#pragma unroll
    for (int d = 0; d < 4; ++d) O[d] = zero4;
    float m2 = -1e30f, lsum = 0.f;
    int nt = qt + 1;

    gload16(kbase + kof, &Ks[0][w << 9]);
    gload16(kbase + 32 * D3 + kof, &Ks[0][2048 + (w << 9)]);
    gload16(vbase + vof, &Vs[0][w << 9]);
    gload16(vbase + vof + 32, &Vs[0][2048 + (w << 9)]);
    __syncthreads();

    int buf = 0;
    for (int it = 0; it < nt; ++it) {
      if (it + 1 < nt) {
        long off = (long)(it + 1) * 64 * D3;
        gload16(kbase + off + kof, &Ks[buf ^ 1][w << 9]);
        gload16(kbase + off + 32 * D3 + kof, &Ks[buf ^ 1][2048 + (w << 9)]);
        gload16(vbase + off + vof, &Vs[buf ^ 1][w << 9]);
        gload16(vbase + off + vof + 32, &Vs[buf ^ 1][2048 + (w << 9)]);
      }
      // V transpose-reads issued early; latency hides under QK^T + softmax.
      unsigned va = ldsoff(&Vs[buf][0]) + (g << 7) + (m16 << 3);
      bf16x4 t0[4], t1[4], t2[4], t3[4];
#pragma unroll
      for (int d = 0; d < 4; ++d) {
        unsigned a = va + (d << 11);
        TRR(t0[d], a);          // kb = g    -> keys 4g..4g+3
        TRR(t1[d], a + 512);    // kb = g+4  -> keys 16+4g..
        TRR(t2[d], a + 1024);   // kb = 8+g  -> keys 32+4g..
        TRR(t3[d], a + 1536);   // kb = 12+g -> keys 48+4g..
      }
      // K fragments (swizzled) + QK^T
      const char* kbuf = (const char*)&Ks[buf][0];
      int swz = m16 & 7;
      bf16x8 kf0[4], kf1[4];
#pragma unroll
      for (int T = 0; T < 4; ++T) {
        const char* rp = kbuf + (((T << 4) + m16) << 7);
        kf0[T] = *(const bf16x8*)(rp + ((g ^ swz) << 4));
        kf1[T] = *(const bf16x8*)(rp + (((4 + g) ^ swz) << 4));
      }
      f32x4 st[4];
      __builtin_amdgcn_s_setprio(1);
#pragma unroll
      for (int T = 0; T < 4; ++T) {
        st[T] = MFMA16x16x32(kf0[T], qf0, zero4);
        st[T] = MFMA16x16x32(kf1[T], qf1, st[T]);
      }
      __builtin_amdgcn_s_setprio(0);

      // C layout: col = q = m16, row(T,g,r) -> key = it*64 + T*16 + g*4 + r
      if (it == nt - 1) {  // diagonal tile (wave-uniform branch)
        int rq = (w << 4) + m16;
#pragma unroll
        for (int T = 0; T < 4; ++T)
#pragma unroll
          for (int r = 0; r < 4; ++r)
            if ((T << 4) + (g << 2) + r > rq) st[T][r] = -3e38f;
      }
      float tmax = max3f(st[0][0], st[0][1], st[0][2]);
      tmax = max3f(tmax, st[0][3], st[1][0]);
      tmax = max3f(tmax, st[1][1], st[1][2]);
      tmax = max3f(tmax, st[1][3], st[2][0]);
      tmax = max3f(tmax, st[2][1], st[2][2]);
      tmax = max3f(tmax, st[2][3], st[3][0]);
      tmax = max3f(tmax, st[3][1], st[3][2]);
      tmax = fmaxf(tmax, st[3][3]);
      tmax = fmaxf(tmax, __shfl_xor(tmax, 16));
      tmax = fmaxf(tmax, __shfl_xor(tmax, 32));
      float tsc2 = tmax * C1;
      bool skip = __all(tsc2 <= m2 + THR);  // defer-max (T13)
      float mnew2 = skip ? m2 : fmaxf(m2, tsc2);
      float p[4][4];
      float tsum = 0.f;
#pragma unroll
      for (int T = 0; T < 4; ++T)
#pragma unroll
        for (int r = 0; r < 4; ++r) {
          float e = __builtin_amdgcn_exp2f(fmaf(st[T][r], C1, -mnew2));
          p[T][r] = e;
          tsum += e;
        }
      tsum += __shfl_xor(tsum, 16);
      tsum += __shfl_xor(tsum, 32);
      if (!skip) {
        float alpha = __builtin_amdgcn_exp2f(m2 - mnew2);
        lsum *= alpha;
#pragma unroll
        for (int d = 0; d < 4; ++d) {
          O[d][0] *= alpha; O[d][1] *= alpha; O[d][2] *= alpha; O[d][3] *= alpha;
        }
        m2 = mnew2;
      }
      lsum += tsum;

      i32x4 w0, w1;
      w0[0] = cvtpk(p[0][0], p[0][1]); w0[1] = cvtpk(p[0][2], p[0][3]);
      w0[2] = cvtpk(p[1][0], p[1][1]); w0[3] = cvtpk(p[1][2], p[1][3]);
      w1[0] = cvtpk(p[2][0], p[2][1]); w1[1] = cvtpk(p[2][2], p[2][3]);
      w1[2] = cvtpk(p[3][0], p[3][1]); w1[3] = cvtpk(p[3][2], p[3][3]);
      bf16x8 pb0 = __builtin_bit_cast(bf16x8, w0);
      bf16x8 pb1 = __builtin_bit_cast(bf16x8, w1);

      asm volatile("s_waitcnt lgkmcnt(0)" ::: "memory");
      __builtin_amdgcn_sched_barrier(0);

      bf16x8 vfA[4], vfB[4];
#pragma unroll
      for (int d = 0; d < 4; ++d) {
        vfA[d] = __builtin_shufflevector(t0[d], t1[d], 0, 1, 2, 3, 4, 5, 6, 7);
        vfB[d] = __builtin_shufflevector(t2[d], t3[d], 0, 1, 2, 3, 4, 5, 6, 7);
      }
      __builtin_amdgcn_s_setprio(1);
#pragma unroll
      for (int d = 0; d < 4; ++d) {
        O[d] = MFMA16x16x32(vfA[d], pb0, O[d]);
        O[d] = MFMA16x16x32(vfB[d], pb1, O[d]);
      }
      __builtin_amdgcn_s_setprio(0);
      __syncthreads();
      buf ^= 1;
    }

    float inv = 1.0f / lsum;
    unsigned short* op = out + (long)(b * 2048 + qrow) * 1024 + h * 64;
#pragma unroll
    for (int d = 0; d < 4; ++d) {
      i32x2 pk;
      pk[0] = (int)cvtpk(O[d][0] * inv, O[d][1] * inv);
      pk[1] = (int)cvtpk(O[d][2] * inv, O[d][3] * inv);
      *reinterpret_cast<i32x2*>(op + (d << 4) + (g << 2)) = pk;
    }
  }
}

extern "C" void kernel_launch(void* const* d_in, const int* in_sizes, int n_in,
                              void* d_out, int out_size, void* d_ws, size_t ws_size,
                              hipStream_t stream) {
  const float* x     = (const float*)d_in[0];
  const float* W_qkv = (const float*)d_in[1];
  const float* b_qkv = (const float*)d_in[2];
  const float* W_out = (const float*)d_in[3];
  const float* b_out = (const float*)d_in[4];

  char* ws = (char*)d_ws;
  unsigned short* xb    = (unsigned short*)ws;                  // 8 MB (x bf16; reused as attn out)
  unsigned short* wqkvT = (unsigned short*)(ws + (8l << 20));   // 6 MB
  unsigned short* woutT = (unsigned short*)(ws + (14l << 20));  // 2 MB
  unsigned short* qkv   = (unsigned short*)(ws + (16l << 20));  // 24 MB

  conv_bf16<<<2048, 256, 0, stream>>>(x, xb, 524288);
  trans_f32_bf16<<<dim3(96, 32), dim3(32, 8), 0, stream>>>(W_qkv, wqkvT, 1024, 3072);
  trans_f32_bf16<<<dim3(32, 32), dim3(32, 8), 0, stream>>>(W_out, woutT, 1024, 1024);
  gemm_bt<1><<<dim3(24, 32), 256, 0, stream>>>(xb, wqkvT, b_qkv, (void*)qkv, 4096, 3072, 1024);
  attn_fwd<<<dim3(32, 16), 256, 0, stream>>>(qkv, xb);
  gemm_bt<0><<<dim3(8, 32), 256, 0, stream>>>(xb, woutT, b_out, d_out, 4096, 1024, 1024);
}

// Round 7
// 118.180 us; speedup vs baseline: 1.5816x; 1.0068x over previous
//
#include <hip/hip_runtime.h>

typedef short bf16x8 __attribute__((ext_vector_type(8)));
typedef short bf16x4 __attribute__((ext_vector_type(4)));
typedef float f32x4 __attribute__((ext_vector_type(4)));
typedef int i32x4 __attribute__((ext_vector_type(4)));
typedef int i32x2 __attribute__((ext_vector_type(2)));

#define MFMA16x16x32(a, b, c) __builtin_amdgcn_mfma_f32_16x16x32_bf16(a, b, c, 0, 0, 0)
#define TRR(dst, a) asm volatile("ds_read_b64_tr_b16 %0, %1" : "=v"(dst) : "v"(a))

__device__ __forceinline__ unsigned short f2bf(float f) {
  union { float f; unsigned u; } v; v.f = f;
  unsigned u = v.u + 0x7FFFu + ((v.u >> 16) & 1u);
  return (unsigned short)(u >> 16);
}

__device__ __forceinline__ unsigned cvtpk(float lo, float hi) {
  unsigned r;
  asm("v_cvt_pk_bf16_f32 %0, %1, %2" : "=v"(r) : "v"(lo), "v"(hi));
  return r;
}

__device__ __forceinline__ float max3f(float a, float b, float c) {
  float d;
  asm("v_max3_f32 %0, %1, %2, %3" : "=v"(d) : "v"(a), "v"(b), "v"(c));
  return d;
}

__device__ __forceinline__ void gload16(const void* g, void* l) {
  __builtin_amdgcn_global_load_lds((const __attribute__((address_space(1))) void*)g,
                                   (__attribute__((address_space(3))) void*)l, 16, 0, 0);
}

__device__ __forceinline__ unsigned ldsoff(const void* p) {
  return (unsigned)(unsigned long long)(const __attribute__((address_space(3))) void*)p;
}

// ---------------- fp32 -> bf16 elementwise (x) ----------------
__global__ __launch_bounds__(256) void conv_bf16(const float* __restrict__ in,
                                                 unsigned short* __restrict__ out, int n8) {
  int i = blockIdx.x * 256 + threadIdx.x;
  if (i >= n8) return;
  const float4* p = reinterpret_cast<const float4*>(in + (long)i * 8);
  float4 a = p[0], b = p[1];
  i32x4 o;
  o[0] = cvtpk(a.x, a.y); o[1] = cvtpk(a.z, a.w);
  o[2] = cvtpk(b.x, b.y); o[3] = cvtpk(b.z, b.w);
  *reinterpret_cast<i32x4*>(out + (long)i * 8) = o;
}

// ---------------- transpose + convert: W[K][N] f32 -> Wt[N][K] bf16 ----------------
__global__ __launch_bounds__(256) void trans_f32_bf16(const float* __restrict__ W,
                                                      unsigned short* __restrict__ Wt,
                                                      int K, int N) {
  __shared__ float tile[32][33];
  int n0 = blockIdx.x << 5, k0 = blockIdx.y << 5;
  int tx = threadIdx.x, ty = threadIdx.y;  // 32 x 8
#pragma unroll
  for (int i = 0; i < 32; i += 8)
    tile[ty + i][tx] = W[(long)(k0 + ty + i) * N + n0 + tx];
  __syncthreads();
#pragma unroll
  for (int i = 0; i < 32; i += 8)
    Wt[(long)(n0 + ty + i) * K + k0 + tx] = f2bf(tile[tx][ty + i]);
}

// ---------------- GEMM: C[M,N] = A[M,K] @ Bt[N,K]^T + bias, bf16 inputs ----------------
template <int BF16OUT>
__global__ __launch_bounds__(256) void gemm_bt(const unsigned short* __restrict__ A,
                                               const unsigned short* __restrict__ Bt,
                                               const float* __restrict__ bias,
                                               void* __restrict__ Cv,
                                               int M, int N, int K) {
  __shared__ __align__(128) unsigned short As[4096];  // [128][32]
  __shared__ __align__(128) unsigned short Bs[4096];  // [128][32]
  int t = threadIdx.x;
  int w = t >> 6, l = t & 63;
  int g = l >> 4, m16 = l & 15;
  int wr = w >> 1, wc = w & 1;
  long am0 = (long)blockIdx.y << 7;
  long bn0 = (long)blockIdx.x << 7;
  f32x4 acc[4][4];
#pragma unroll
  for (int i = 0; i < 4; ++i)
#pragma unroll
    for (int j = 0; j < 4; ++j) acc[i][j] = (f32x4){0.f, 0.f, 0.f, 0.f};

  for (int k0 = 0; k0 < K; k0 += 32) {
#pragma unroll
    for (int i = 0; i < 2; ++i) {
      int seg = i * 4 + w;
      int flat = (seg << 9) + (l << 3);
      int r_ = flat >> 5, c_ = flat & 31;
      gload16(A + (am0 + r_) * K + k0 + c_, &As[seg << 9]);
      gload16(Bt + (bn0 + r_) * K + k0 + c_, &Bs[seg << 9]);
    }
    __syncthreads();
    bf16x8 af[4], bfr[4];
#pragma unroll
    for (int im = 0; im < 4; ++im)
      af[im] = *(const bf16x8*)&As[((wr << 6) + (im << 4) + m16) * 32 + (g << 3)];
#pragma unroll
    for (int in = 0; in < 4; ++in)
      bfr[in] = *(const bf16x8*)&Bs[((wc << 6) + (in << 4) + m16) * 32 + (g << 3)];
    __builtin_amdgcn_s_setprio(1);
#pragma unroll
    for (int im = 0; im < 4; ++im)
#pragma unroll
      for (int in = 0; in < 4; ++in)
        acc[im][in] = MFMA16x16x32(af[im], bfr[in], acc[im][in]);
    __builtin_amdgcn_s_setprio(0);
    __syncthreads();
  }

#pragma unroll
  for (int im = 0; im < 4; ++im) {
#pragma unroll
    for (int in = 0; in < 4; ++in) {
      long col = bn0 + (wc << 6) + (in << 4) + m16;
      float bval = bias[col];
#pragma unroll
      for (int r = 0; r < 4; ++r) {
        long row = am0 + (wr << 6) + (im << 4) + (g << 2) + r;
        float v = acc[im][in][r] + bval;
        if (BF16OUT)
          ((unsigned short*)Cv)[row * N + col] = f2bf(v);
        else
          ((float*)Cv)[row * N + col] = v;
      }
    }
  }
}

// ---------------- causal flash attention (KVBLK=128 supersteps, paired q-tiles) ------
// grid: (B*H=32, 16), block 256 (4 waves). Block y handles q-tiles {y, 31-y}
// sequentially: ceil((y+1)/2) + ceil((32-y)/2) = 17 supersteps for EVERY block.
// K tile [128 rows][64 d] LDS (16KB), XOR-swizzled 16B chunks (chunk ^= row&7).
// V tile as 128 subtiles [db 4][kb 32][4key][16d] (128B each, 16KB) for tr_b16 reads.
// Per superstep: 16 QK MFMA + ONE softmax round + 16 PV MFMA (amortizes the
// shuffle-reduce/defer/rescale chain over 128 keys).
__global__ __launch_bounds__(256, 2) void attn_fwd(const unsigned short* __restrict__ qkv,
                                                   unsigned short* __restrict__ out) {
  const int D3 = 3072;
  const float C1 = 0.18033688f;    // 0.125 * log2(e)
  const float THR = 11.5415603f;   // 8 * log2(e)
  __shared__ __align__(128) unsigned short Ks[2][8192];
  __shared__ __align__(128) unsigned short Vs[2][8192];
  int b = blockIdx.x >> 4, h = blockIdx.x & 15;
  int t = threadIdx.x;
  int w = t >> 6, l = t & 63;
  int g = l >> 4, m16 = l & 15;
  long base = (long)b * 2048 * D3;
  const unsigned short* kbase = qkv + base + 1024 + h * 64;
  const unsigned short* vbase = qkv + base + 2048 + h * 64;

  // staging offsets (loop-invariant): each thread stages 4 K chunks + 4 V chunks.
  // load i covers rows/subtiles i*32 + w*8 + l8; row&7 == l8 for all i.
  int l8 = l >> 3, sc = l & 7;
  int kof = (w * 8 + l8) * D3 + ((sc ^ l8) << 3);
  int vof = ((w * 8 + l8) * 4 + (sc >> 1)) * D3 + ((sc & 1) << 3);
  const f32x4 zero4 = (f32x4){0.f, 0.f, 0.f, 0.f};

  for (int sgi = 0; sgi < 2; ++sgi) {
    int qt = sgi ? (31 - blockIdx.y) : blockIdx.y;
    int q0 = qt << 6;
    int qrow = q0 + (w << 4) + m16;
    const unsigned short* qp = qkv + base + (long)qrow * D3 + h * 64;
    bf16x8 qf0 = *(const bf16x8*)(qp + g * 8);
    bf16x8 qf1 = *(const bf16x8*)(qp + 32 + g * 8);

    f32x4 O[4];
#pragma unroll
    for (int d = 0; d < 4; ++d) O[d] = zero4;
    float m2 = -1e30f, lsum = 0.f;
    int nt = (qt >> 1) + 1;  // supersteps of 128 keys

#pragma unroll
    for (int i = 0; i < 4; ++i) {
      gload16(kbase + kof + i * 32 * D3, &Ks[0][(i << 11) + (w << 9)]);
      gload16(vbase + vof + (i << 4), &Vs[0][(i << 11) + (w << 9)]);
    }
    __syncthreads();

    int buf = 0;
    for (int it = 0; it < nt; ++it) {
      if (it + 1 < nt) {
        long off = (long)(it + 1) * 128 * D3;
#pragma unroll
        for (int i = 0; i < 4; ++i) {
          gload16(kbase + off + kof + i * 32 * D3, &Ks[buf ^ 1][(i << 11) + (w << 9)]);
          gload16(vbase + off + vof + (i << 4), &Vs[buf ^ 1][(i << 11) + (w << 9)]);
        }
      }
      // V transpose-reads issued early; latency hides under QK^T + softmax.
      unsigned va = ldsoff(&Vs[buf][0]) + (g << 7) + (m16 << 3);
      bf16x4 tLo[4][4], tHi[4][4];  // [G 32-key group][d block]
#pragma unroll
      for (int G = 0; G < 4; ++G)
#pragma unroll
        for (int d = 0; d < 4; ++d) {
          unsigned a = va + (G << 10) + (d << 12);
          TRR(tLo[G][d], a);        // kb = 8G+g   -> keys 32G+4g..+3
          TRR(tHi[G][d], a + 512);  // kb = 8G+g+4 -> keys 32G+16+4g..+3
        }
      // K fragments (swizzled) + QK^T
      const char* kbuf = (const char*)&Ks[buf][0];
      int swz = m16 & 7;
      f32x4 st[8];
      __builtin_amdgcn_s_setprio(1);
#pragma unroll
      for (int T = 0; T < 8; ++T) {
        const char* rp = kbuf + (((T << 4) + m16) << 7);
        bf16x8 kf0 = *(const bf16x8*)(rp + ((g ^ swz) << 4));
        bf16x8 kf1 = *(const bf16x8*)(rp + (((4 + g) ^ swz) << 4));
        st[T] = MFMA16x16x32(kf0, qf0, zero4);
        st[T] = MFMA16x16x32(kf1, qf1, st[T]);
      }
      __builtin_amdgcn_s_setprio(0);

      // C layout: col = q = m16, row(T,g,r) -> key = it*128 + T*16 + g*4 + r
      if (it == nt - 1) {  // diagonal superstep (wave-uniform branch)
        int rq = qrow - (it << 7);
#pragma unroll
        for (int T = 0; T < 8; ++T)
#pragma unroll
          for (int r = 0; r < 4; ++r)
            if ((T << 4) + (g << 2) + r > rq) st[T][r] = -3e38f;
      }
      float tm[8];
#pragma unroll
      for (int T = 0; T < 8; ++T)
        tm[T] = max3f(fmaxf(st[T][0], st[T][1]), st[T][2], st[T][3]);
      float u0 = max3f(tm[0], tm[1], tm[2]);
      float u1 = max3f(tm[3], tm[4], tm[5]);
      float tmax = max3f(u0, u1, fmaxf(tm[6], tm[7]));
      tmax = fmaxf(tmax, __shfl_xor(tmax, 16));
      tmax = fmaxf(tmax, __shfl_xor(tmax, 32));
      float tsc2 = tmax * C1;
      bool skip = __all(tsc2 <= m2 + THR);  // defer-max (T13)
      float mnew2 = skip ? m2 : fmaxf(m2, tsc2);
      float p[8][4];
      f32x4 ts4 = zero4;
#pragma unroll
      for (int T = 0; T < 8; ++T)
#pragma unroll
        for (int r = 0; r < 4; ++r) {
          float e = __builtin_amdgcn_exp2f(fmaf(st[T][r], C1, -mnew2));
          p[T][r] = e;
          ts4[r] += e;
        }
      float tsum = (ts4[0] + ts4[1]) + (ts4[2] + ts4[3]);
      tsum += __shfl_xor(tsum, 16);
      tsum += __shfl_xor(tsum, 32);
      if (!skip) {
        float alpha = __builtin_amdgcn_exp2f(m2 - mnew2);
        lsum *= alpha;
#pragma unroll
        for (int d = 0; d < 4; ++d) {
          O[d][0] *= alpha; O[d][1] *= alpha; O[d][2] *= alpha; O[d][3] *= alpha;
        }
        m2 = mnew2;
      }
      lsum += tsum;

      bf16x8 pb[4];
#pragma unroll
      for (int G = 0; G < 4; ++G) {
        i32x4 wv;
        wv[0] = cvtpk(p[2 * G][0], p[2 * G][1]);
        wv[1] = cvtpk(p[2 * G][2], p[2 * G][3]);
        wv[2] = cvtpk(p[2 * G + 1][0], p[2 * G + 1][1]);
        wv[3] = cvtpk(p[2 * G + 1][2], p[2 * G + 1][3]);
        pb[G] = __builtin_bit_cast(bf16x8, wv);
      }

      asm volatile("s_waitcnt lgkmcnt(0)" ::: "memory");
      __builtin_amdgcn_sched_barrier(0);

      __builtin_amdgcn_s_setprio(1);
#pragma unroll
      for (int d = 0; d < 4; ++d)
#pragma unroll
        for (int G = 0; G < 4; ++G) {
          bf16x8 vf = __builtin_shufflevector(tLo[G][d], tHi[G][d], 0, 1, 2, 3, 4, 5, 6, 7);
          O[d] = MFMA16x16x32(vf, pb[G], O[d]);
        }
      __builtin_amdgcn_s_setprio(0);
      __syncthreads();
      buf ^= 1;
    }

    float inv = 1.0f / lsum;
    unsigned short* op = out + (long)(b * 2048 + qrow) * 1024 + h * 64;
#pragma unroll
    for (int d = 0; d < 4; ++d) {
      i32x2 pk;
      pk[0] = (int)cvtpk(O[d][0] * inv, O[d][1] * inv);
      pk[1] = (int)cvtpk(O[d][2] * inv, O[d][3] * inv);
      *reinterpret_cast<i32x2*>(op + (d << 4) + (g << 2)) = pk;
    }
  }
}

extern "C" void kernel_launch(void* const* d_in, const int* in_sizes, int n_in,
                              void* d_out, int out_size, void* d_ws, size_t ws_size,
                              hipStream_t stream) {
  const float* x     = (const float*)d_in[0];
  const float* W_qkv = (const float*)d_in[1];
  const float* b_qkv = (const float*)d_in[2];
  const float* W_out = (const float*)d_in[3];
  const float* b_out = (const float*)d_in[4];

  char* ws = (char*)d_ws;
  unsigned short* xb    = (unsigned short*)ws;                  // 8 MB (x bf16; reused as attn out)
  unsigned short* wqkvT = (unsigned short*)(ws + (8l << 20));   // 6 MB
  unsigned short* woutT = (unsigned short*)(ws + (14l << 20));  // 2 MB
  unsigned short* qkv   = (unsigned short*)(ws + (16l << 20));  // 24 MB

  conv_bf16<<<2048, 256, 0, stream>>>(x, xb, 524288);
  trans_f32_bf16<<<dim3(96, 32), dim3(32, 8), 0, stream>>>(W_qkv, wqkvT, 1024, 3072);
  trans_f32_bf16<<<dim3(32, 32), dim3(32, 8), 0, stream>>>(W_out, woutT, 1024, 1024);
  gemm_bt<1><<<dim3(24, 32), 256, 0, stream>>>(xb, wqkvT, b_qkv, (void*)qkv, 4096, 3072, 1024);
  attn_fwd<<<dim3(32, 16), 256, 0, stream>>>(qkv, xb);
  gemm_bt<0><<<dim3(8, 32), 256, 0, stream>>>(xb, woutT, b_out, d_out, 4096, 1024, 1024);
}